// Round 4
// baseline (206.368 us; speedup 1.0000x reference)
//
#include <hip/hip_runtime.h>

typedef float f32x4 __attribute__((ext_vector_type(4)));
typedef short s16x8 __attribute__((ext_vector_type(8)));
typedef unsigned short us4 __attribute__((ext_vector_type(4)));

#define MFMA16(a, b, c) __builtin_amdgcn_mfma_f32_16x16x32_bf16(a, b, c, 0, 0, 0)

// async global->LDS DMA, 16B per lane. LDS dest must be wave-uniform base + lane*16.
#define GLOAD_LDS16(gp, lp) __builtin_amdgcn_global_load_lds( \
    (__attribute__((address_space(1))) void*)(gp),            \
    (__attribute__((address_space(3))) void*)(lp), 16, 0, 0)

__device__ __forceinline__ unsigned short f2bf(float f) {
    union { float f; unsigned u; } v; v.f = f;
    unsigned r = v.u + 0x7fffu + ((v.u >> 16) & 1u);   // RNE truncate to bf16
    return (unsigned short)(r >> 16);
}

// Repack tile row stride: 136 shorts = 272B (16B-aligned rows, odd-ish bank
// stride so scalar ds_writes are ~2-way and b128 readback ~4-way).
#define RP 136
// shared size for 128x128 GEMM kernels: gemm needs 8192 shorts, repack 128*RP.
#define SH128 (128 * RP)

// ---------------------------------------------------------------------------
// m97-style GEMM core (VERIFIED round-1 structure, single-buffer, 2 barriers):
// C += A[128xK] @ B[128xK]^T. 256 thr = 4 waves in 2x2 quadrants of 64x64.
// NOTE: no trailing barrier — callers must __syncthreads() before reusing LDS.
// ---------------------------------------------------------------------------
__device__ __forceinline__ void gemm_core128(
    const unsigned short* __restrict__ Ab, size_t Astride,
    const unsigned short* __restrict__ Bb, size_t Bstride,
    int K, unsigned short* As, unsigned short* Bs,
    int t, f32x4 acc[4][4])
{
    const int wave = t >> 6, lane = t & 63;
    const int c = lane & 15, quad = lane >> 4;
    const int wm = (wave >> 1) * 64, wn = (wave & 1) * 64;
    const int srow = t >> 2;
    const int scol = (t & 3) * 8;

    for (int k0 = 0; k0 < K; k0 += 32) {
        __syncthreads();
        const unsigned short* ga = Ab + (size_t)srow * Astride + k0 + scol;
        const unsigned short* gb = Bb + (size_t)srow * Bstride + k0 + scol;
        GLOAD_LDS16(ga,                 As + t * 8);
        GLOAD_LDS16(ga + 64 * Astride,  As + 2048 + t * 8);
        GLOAD_LDS16(gb,                 Bs + t * 8);
        GLOAD_LDS16(gb + 64 * Bstride,  Bs + 2048 + t * 8);
        __syncthreads();

        s16x8 af[4], bf[4];
        #pragma unroll
        for (int i = 0; i < 4; i++)
            af[i] = *(const s16x8*)(As + (wm + i * 16 + c) * 32 + quad * 8);
        #pragma unroll
        for (int i = 0; i < 4; i++)
            bf[i] = *(const s16x8*)(Bs + (wn + i * 16 + c) * 32 + quad * 8);
        #pragma unroll
        for (int mt = 0; mt < 4; mt++)
            #pragma unroll
            for (int nt = 0; nt < 4; nt++)
                acc[mt][nt] = MFMA16(af[mt], bf[nt], acc[mt][nt]);
    }
}

// ---------------------------------------------------------------------------
// Kernel 1: convert x -> bf16 row-major; W{q,k,v} -> bf16 transposed [n][k]
// via 64x64 LDS-transpose tiles. Grid 4288: [0,4096) x, [4096,4288) weights.
// (lg accumulator eliminated — k_out self-computes the denominator.)
// ---------------------------------------------------------------------------
__global__ __launch_bounds__(256) void k_convert(
    const float* __restrict__ x, const float* __restrict__ wq,
    const float* __restrict__ wk, const float* __restrict__ wv,
    unsigned short* __restrict__ xbf, unsigned short* __restrict__ wt)
{
    __shared__ __align__(16) unsigned short lt[64][72];   // 64x64 tile, padded

    int bid = blockIdx.x, t = threadIdx.x;
    if (bid < 4096) {
        int gid = bid * 256 + t;
        float4 v = ((const float4*)x)[gid];
        us4 o = { f2bf(v.x), f2bf(v.y), f2bf(v.z), f2bf(v.w) };
        ((us4*)xbf)[gid] = o;
    } else {
        int idx = bid - 4096;
        int w = idx >> 6;                    // 0=q 1=k 2=v
        int tile = idx & 63;
        int tk = tile >> 3, tn = tile & 7;   // 8x8 tiles of 64x64 over [512][512]
        const float* src = ((w == 0) ? wq : (w == 1) ? wk : wv)
                         + (size_t)(tk * 64) * 512 + tn * 64;

        int row = t >> 2;
        int c0 = (t & 3) * 16;
        const float4* s = (const float4*)(src + (size_t)row * 512 + c0);
        #pragma unroll
        for (int q = 0; q < 4; q++) {
            float4 v = s[q];
            lt[c0 + q * 4 + 0][row] = f2bf(v.x);
            lt[c0 + q * 4 + 1][row] = f2bf(v.y);
            lt[c0 + q * 4 + 2][row] = f2bf(v.z);
            lt[c0 + q * 4 + 3][row] = f2bf(v.w);
        }
        __syncthreads();

        int n = t >> 2;
        int k0 = (t & 3) * 16;
        s16x8 a = *(const s16x8*)&lt[n][k0];
        s16x8 b = *(const s16x8*)&lt[n][k0 + 8];
        unsigned short* dst = wt + (((size_t)(w * 512 + tn * 64 + n)) << 9)
                                 + tk * 64 + k0;
        *(s16x8*)dst = a;
        *(s16x8*)(dst + 8) = b;
    }
}

// ---------------------------------------------------------------------------
// Kernel 2: QKV projection. [8192x512] @ [1536x512]^T. Grid (64,12).
// All epilogues repack through LDS for coalesced vector stores.
// ---------------------------------------------------------------------------
__global__ __launch_bounds__(256) void k_proj(
    const unsigned short* __restrict__ xbf, const unsigned short* __restrict__ wt,
    unsigned short* __restrict__ qbf, unsigned short* __restrict__ kbf,
    unsigned short* __restrict__ vtbf)
{
    __shared__ __align__(16) unsigned short sh[SH128];

    int t = threadIdx.x;
    int m0 = blockIdx.x * 128, n0 = blockIdx.y * 128;
    f32x4 acc[4][4] = {};

    gemm_core128(xbf + (size_t)m0 * 512, 512, wt + (size_t)n0 * 512, 512,
                 512, sh, sh + 4096, t, acc);
    __syncthreads();   // gemm core has no trailing barrier; LDS reuse below

    int wave = t >> 6, lane = t & 63, c = lane & 15, quad = lane >> 4;
    int wm = (wave >> 1) * 64, wn = (wave & 1) * 64;
    int sel = blockIdx.y >> 2;                    // 0=q 1=k 2=v

    if (sel < 2) {
        unsigned short* dst = sel ? kbf : qbf;
        int ncol0 = n0 - sel * 512;
        #pragma unroll
        for (int mt = 0; mt < 4; mt++)
            #pragma unroll
            for (int nt = 0; nt < 4; nt++)
                #pragma unroll
                for (int r = 0; r < 4; r++)
                    sh[(wm + mt * 16 + quad * 4 + r) * RP + wn + nt * 16 + c]
                        = f2bf(acc[mt][nt][r]);
        __syncthreads();
        // FIXED (was the R2/R3 bug): each thread owns 64 shorts = 8 vectors,
        // not 4 — half the tile was previously never written to global.
        int rr = t >> 1, hh = (t & 1) * 64;
        const s16x8* sp = (const s16x8*)(sh + rr * RP + hh);
        s16x8* dp = (s16x8*)(dst + (size_t)(m0 + rr) * 512 + ncol0 + hh);
        s16x8 v[8];
        #pragma unroll
        for (int i = 0; i < 8; i++) v[i] = sp[i];
        #pragma unroll
        for (int i = 0; i < 8; i++) dp[i] = v[i];
    } else {
        // V: repack transposed in LDS -> 128B-contiguous stores per thread.
        #pragma unroll
        for (int mt = 0; mt < 4; mt++)
            #pragma unroll
            for (int nt = 0; nt < 4; nt++)
                #pragma unroll
                for (int r = 0; r < 4; r++)
                    sh[(wn + nt * 16 + c) * RP + wm + mt * 16 + quad * 4 + r]
                        = f2bf(acc[mt][nt][r]);
        __syncthreads();
        int bb = m0 >> 11, nn0 = m0 & 2047;
        int dbase = n0 - 1024;
        int dl = t >> 1, nh = (t & 1) * 64;
        const s16x8* sp = (const s16x8*)(sh + dl * RP + nh);
        s16x8* dp = (s16x8*)(vtbf + ((size_t)(bb * 512 + dbase + dl)) * 2048
                                  + nn0 + nh);
        s16x8 v[8];
        #pragma unroll
        for (int i = 0; i < 8; i++) v[i] = sp[i];
        #pragma unroll
        for (int i = 0; i < 8; i++) dp[i] = v[i];
    }
}

// ---------------------------------------------------------------------------
// score body: S = Q@K^T (128x128 tile), P = exp(S*scale) -> bf16 via LDS
// repack (coalesced 16B stores). No l accumulation — k_out self-computes it.
// ---------------------------------------------------------------------------
__device__ __forceinline__ void score_body(
    const unsigned short* __restrict__ qbf, const unsigned short* __restrict__ kbf,
    unsigned short* __restrict__ pbf,
    int b, int m0, int n0, int t, unsigned short* sh)
{
    f32x4 acc[4][4] = {};
    gemm_core128(qbf + (size_t)(b * 2048 + m0) * 512, 512,
                 kbf + (size_t)(b * 2048 + n0) * 512, 512,
                 512, sh, sh + 4096, t, acc);
    __syncthreads();   // gemm core has no trailing barrier; LDS reuse below

    int wave = t >> 6, lane = t & 63, c = lane & 15, quad = lane >> 4;
    int wm = (wave >> 1) * 64, wn = (wave & 1) * 64;
    const float scale = 0.044194173824159216f;    // 1/sqrt(512)

    #pragma unroll
    for (int mt = 0; mt < 4; mt++) {
        #pragma unroll
        for (int r = 0; r < 4; r++) {
            int row = wm + mt * 16 + quad * 4 + r;    // local 0..127
            #pragma unroll
            for (int nt = 0; nt < 4; nt++) {
                float p = __expf(acc[mt][nt][r] * scale);
                sh[row * RP + wn + nt * 16 + c] = f2bf(p);
            }
        }
    }
    __syncthreads();
    // FIXED: 8 vectors per thread (64 shorts), full tile coverage.
    int rr = t >> 1, hh = (t & 1) * 64;
    const s16x8* sp = (const s16x8*)(sh + rr * RP + hh);
    s16x8* dp = (s16x8*)(pbf + (size_t)(b * 2048 + m0 + rr) * 2048 + n0 + hh);
    s16x8 v[8];
    #pragma unroll
    for (int i = 0; i < 8; i++) v[i] = sp[i];
    #pragma unroll
    for (int i = 0; i < 8; i++) dp[i] = v[i];
}

// ---------------------------------------------------------------------------
// prior: one WAVE per (b,i) row — no LDS, no barriers, no atomics.
// ---------------------------------------------------------------------------
__device__ __forceinline__ void prior_wave(
    const float* __restrict__ x, const float* __restrict__ wsv,
    float* __restrict__ pout, int row, int lane)
{
    const float4* xr = (const float4*)(x + (size_t)row * 512);
    const float4* wr = (const float4*)wsv;
    float4 a0 = xr[lane * 2],     b0 = wr[lane * 2];
    float4 a1 = xr[lane * 2 + 1], b1 = wr[lane * 2 + 1];
    float part = a0.x * b0.x + a0.y * b0.y + a0.z * b0.z + a0.w * b0.w
               + a1.x * b1.x + a1.y * b1.y + a1.z * b1.z + a1.w * b1.w;
    #pragma unroll
    for (int o = 32; o; o >>= 1) part += __shfl_xor(part, o, 64);
    float sigma = part;
    float inv2 = 0.5f / (sigma * sigma);

    int i = row & 2047;
    float g[32];
    float sum = 0.f;
    #pragma unroll
    for (int u = 0; u < 8; u++) {
        #pragma unroll
        for (int v = 0; v < 4; v++) {
            float d = (float)(u * 256 + lane * 4 + v - i);
            float e = __expf(-(d * d) * inv2);
            g[u * 4 + v] = e;
            sum += e;
        }
    }
    #pragma unroll
    for (int o = 32; o; o >>= 1) sum += __shfl_xor(sum, o, 64);
    float inv = 1.0f / sum;

    float4* pr = (float4*)(pout + (size_t)row * 2048);
    #pragma unroll
    for (int u = 0; u < 8; u++) {
        float4 o4 = { g[u * 4] * inv, g[u * 4 + 1] * inv,
                      g[u * 4 + 2] * inv, g[u * 4 + 3] * inv };
        pr[u * 64 + lane] = o4;
    }
}

// ---------------------------------------------------------------------------
// Kernel 3a (ws path): merged score + prior. Grid 3072 1D.
// ---------------------------------------------------------------------------
__global__ __launch_bounds__(256) void k_score_prior(
    const unsigned short* __restrict__ qbf, const unsigned short* __restrict__ kbf,
    unsigned short* __restrict__ pbf,
    const float* __restrict__ x, const float* __restrict__ wsv,
    float* __restrict__ pout)
{
    __shared__ __align__(16) unsigned short sh[SH128];

    int bid = blockIdx.x, t = threadIdx.x;
    if (bid < 1024) {
        int b = bid >> 8, r = bid & 255;
        score_body(qbf, kbf, pbf, b, (r & 15) * 128, (r >> 4) * 128, t, sh);
    } else {
        int row = (bid - 1024) * 4 + (t >> 6);
        prior_wave(x, wsv, pout, row, t & 63);
    }
}

// ---------------------------------------------------------------------------
// Kernel 3b (fallback): standalone score. Grid (16,16,4).
// ---------------------------------------------------------------------------
__global__ __launch_bounds__(256) void k_score(
    const unsigned short* __restrict__ qbf, const unsigned short* __restrict__ kbf,
    unsigned short* __restrict__ pbf)
{
    __shared__ __align__(16) unsigned short sh[SH128];
    score_body(qbf, kbf, pbf, blockIdx.z,
               blockIdx.x * 128, blockIdx.y * 128, threadIdx.x, sh);
}

// ---------------------------------------------------------------------------
// Kernel 4: output. Per batch: O = P @ Vt^T / l. 128x64 tile, grid (16,8,4).
// l is computed in-kernel via a 5th accumulator column with an all-ones bf16
// B fragment: accl[mt] += af[mt] @ ones gives every lane its row's sum of P
// (any B layout works since B==1), so no lg buffer / atomics / shuffles.
// ---------------------------------------------------------------------------
__global__ __launch_bounds__(256) void k_out(
    const unsigned short* __restrict__ pbf, const unsigned short* __restrict__ vtbf,
    float* __restrict__ zout)
{
    __shared__ __align__(16) unsigned short As[128 * 32];   // P tile
    __shared__ __align__(16) unsigned short Bs[64 * 32];    // Vt tile

    int t = threadIdx.x;
    int b = blockIdx.z;
    int m0 = blockIdx.x * 128, n0 = blockIdx.y * 64;

    const int wave = t >> 6, lane = t & 63;
    const int c = lane & 15, quad = lane >> 4;
    const int wm = (wave >> 1) * 64, wn = (wave & 1) * 32;
    const int srow = t >> 2;
    const int scol = (t & 3) * 8;

    const unsigned short* Ab = pbf + (size_t)(b * 2048 + m0) * 2048;
    const unsigned short* Bb = vtbf + (size_t)(b * 512 + n0) * 2048;

    s16x8 ones;
    #pragma unroll
    for (int i = 0; i < 8; i++) ones[i] = (short)0x3F80;    // bf16 1.0

    f32x4 acc[4][2] = {};
    f32x4 accl[4] = {};

    for (int k0 = 0; k0 < 2048; k0 += 32) {
        __syncthreads();
        const unsigned short* ga = Ab + (size_t)srow * 2048 + k0 + scol;
        GLOAD_LDS16(ga,             As + t * 8);
        GLOAD_LDS16(ga + 64 * 2048, As + 2048 + t * 8);
        GLOAD_LDS16(Bb + (size_t)srow * 2048 + k0 + scol, Bs + t * 8);
        __syncthreads();

        s16x8 af[4], bf[2];
        #pragma unroll
        for (int i = 0; i < 4; i++)
            af[i] = *(const s16x8*)(As + (wm + i * 16 + c) * 32 + quad * 8);
        #pragma unroll
        for (int i = 0; i < 2; i++)
            bf[i] = *(const s16x8*)(Bs + (wn + i * 16 + c) * 32 + quad * 8);
        #pragma unroll
        for (int mt = 0; mt < 4; mt++) {
            #pragma unroll
            for (int nt = 0; nt < 2; nt++)
                acc[mt][nt] = MFMA16(af[mt], bf[nt], acc[mt][nt]);
            accl[mt] = MFMA16(af[mt], ones, accl[mt]);
        }
    }

    #pragma unroll
    for (int mt = 0; mt < 4; mt++) {
        #pragma unroll
        for (int r = 0; r < 4; r++) {
            int row = wm + mt * 16 + quad * 4 + r;
            float inv = 1.0f / accl[mt][r];
            #pragma unroll
            for (int nt = 0; nt < 2; nt++) {
                zout[(size_t)(b * 2048 + m0 + row) * 512 + n0 + wn + nt * 16 + c]
                    = acc[mt][nt][r] * inv;
            }
        }
    }
}

// ---------------------------------------------------------------------------
// Kernel 5 (fallback): standalone prior. Grid 2048, 4 rows/block.
// ---------------------------------------------------------------------------
__global__ __launch_bounds__(256) void k_prior(
    const float* __restrict__ x, const float* __restrict__ wsv,
    float* __restrict__ pout)
{
    int row = blockIdx.x * 4 + (threadIdx.x >> 6);
    prior_wave(x, wsv, pout, row, threadIdx.x & 63);
}

// ---------------------------------------------------------------------------
extern "C" void kernel_launch(void* const* d_in, const int* in_sizes, int n_in,
                              void* d_out, int out_size, void* d_ws, size_t ws_size,
                              hipStream_t stream)
{
    const float* x  = (const float*)d_in[0];
    const float* wq = (const float*)d_in[1];
    const float* wk = (const float*)d_in[2];
    const float* wv = (const float*)d_in[3];
    const float* ws = (const float*)d_in[4];

    float* zout = (float*)d_out;                       // (4,2048,512)
    float* pout = zout + (size_t)4 * 2048 * 512;       // (4,2048,2048) = 67.1 MB

    // Scratch: xbf 4.19M + wt 0.79M + q/k/vt 3*4.19M + pbf 16.78M ushorts.
    const size_t need = ((size_t)4194304 + 786432 + 3 * 4194304 + 16777216) * 2;

    if (ws_size >= need) {
        // ---- ws path: all scratch in d_ws; pout free -> prior overlaps score
        unsigned short* base = (unsigned short*)d_ws;
        unsigned short* xbf  = base;
        unsigned short* wt   = xbf  + (size_t)4194304;
        unsigned short* qbf  = wt   + (size_t)786432;
        unsigned short* kbf  = qbf  + (size_t)4194304;
        unsigned short* vtbf = kbf  + (size_t)4194304;
        unsigned short* pbf  = vtbf + (size_t)4194304;

        k_convert<<<dim3(4288), dim3(256), 0, stream>>>(x, wq, wk, wv, xbf, wt);
        k_proj       <<<dim3(64, 12),   dim3(256), 0, stream>>>(xbf, wt, qbf, kbf, vtbf);
        k_score_prior<<<dim3(3072),     dim3(256), 0, stream>>>(qbf, kbf, pbf, x, ws, pout);
        k_out        <<<dim3(16, 8, 4), dim3(256), 0, stream>>>(pbf, vtbf, zout);
    } else {
        // ---- fallback: scratch inside pout (prior runs last)
        unsigned short* base = (unsigned short*)pout;
        unsigned short* pbf  = base;                        // 16,777,216
        unsigned short* qbf  = base + (size_t)16777216;
        unsigned short* kbf  = qbf  + (size_t)4194304;
        unsigned short* vtbf = kbf  + (size_t)4194304;
        unsigned short* xbf  = base;                        // overlaps pbf (ok)
        unsigned short* wt   = base + (size_t)4194304;      // overlaps pbf (ok)

        k_convert<<<dim3(4288), dim3(256), 0, stream>>>(x, wq, wk, wv, xbf, wt);
        k_proj  <<<dim3(64, 12),    dim3(256), 0, stream>>>(xbf, wt, qbf, kbf, vtbf);
        k_score <<<dim3(16, 16, 4), dim3(256), 0, stream>>>(qbf, kbf, pbf);
        k_out   <<<dim3(16, 8, 4),  dim3(256), 0, stream>>>(pbf, vtbf, zout);
        k_prior <<<dim3(2048),      dim3(256), 0, stream>>>(x, ws, pout);
    }
}

// Round 5
// 199.145 us; speedup vs baseline: 1.0363x; 1.0363x over previous
//
#include <hip/hip_runtime.h>

typedef float f32x4 __attribute__((ext_vector_type(4)));
typedef short s16x8 __attribute__((ext_vector_type(8)));
typedef unsigned short us4 __attribute__((ext_vector_type(4)));

#define MFMA16(a, b, c) __builtin_amdgcn_mfma_f32_16x16x32_bf16(a, b, c, 0, 0, 0)

// async global->LDS DMA, 16B per lane. LDS dest must be wave-uniform base + lane*16.
#define GLOAD_LDS16(gp, lp) __builtin_amdgcn_global_load_lds( \
    (__attribute__((address_space(1))) void*)(gp),            \
    (__attribute__((address_space(3))) void*)(lp), 16, 0, 0)

__device__ __forceinline__ unsigned short f2bf(float f) {
    union { float f; unsigned u; } v; v.f = f;
    unsigned r = v.u + 0x7fffu + ((v.u >> 16) & 1u);   // RNE truncate to bf16
    return (unsigned short)(r >> 16);
}

// Repack tile row stride: 136 shorts = 272B (16B-aligned rows, odd-ish bank
// stride so scalar ds_writes are ~2-way and b128 readback ~4-way).
#define RP 136
// shared size for 128x128 GEMM kernels:
// dbuf gemm needs 16384 shorts, repack needs 128*RP = 17408.
#define SH128 (128 * RP)

// ---------------------------------------------------------------------------
// Double-buffered GEMM core, 128x128 tile: C += A[128xK] @ B[128xK]^T.
// sh layout: buf0 A[0,4096) B[4096,8192), buf1 at +8192.
// One barrier per K-step: next tile's global_load_lds issues BEFORE the
// current tile's ds_read+MFMA, so load latency hides under compute.
// Correctness: __syncthreads lowers to s_waitcnt vmcnt(0) lgkmcnt(0) +
// s_barrier, so buffer writes/reads are strictly barrier-separated.
// Ends with a trailing barrier -> callers may reuse sh immediately.
// ---------------------------------------------------------------------------
__device__ __forceinline__ void gemm_core128_db(
    const unsigned short* __restrict__ Ab, size_t Astride,
    const unsigned short* __restrict__ Bb, size_t Bstride,
    int K, unsigned short* sh, int t, f32x4 acc[4][4])
{
    const int wave = t >> 6, lane = t & 63;
    const int c = lane & 15, quad = lane >> 4;
    const int wm = (wave >> 1) * 64, wn = (wave & 1) * 64;
    const int srow = t >> 2;
    const int scol = (t & 3) * 8;

    const unsigned short* ga = Ab + (size_t)srow * Astride + scol;
    const unsigned short* gb = Bb + (size_t)srow * Bstride + scol;

    // prologue: stage k0=0 into buf0
    GLOAD_LDS16(ga,                 sh + t * 8);
    GLOAD_LDS16(ga + 64 * Astride,  sh + 2048 + t * 8);
    GLOAD_LDS16(gb,                 sh + 4096 + t * 8);
    GLOAD_LDS16(gb + 64 * Bstride,  sh + 4096 + 2048 + t * 8);
    __syncthreads();

    int cur = 0;
    for (int k0 = 0; k0 < K; k0 += 32) {
        const unsigned short* buf = sh + cur * 8192;
        if (k0 + 32 < K) {
            unsigned short* nb = sh + (cur ^ 1) * 8192;
            GLOAD_LDS16(ga + k0 + 32,                 nb + t * 8);
            GLOAD_LDS16(ga + k0 + 32 + 64 * Astride,  nb + 2048 + t * 8);
            GLOAD_LDS16(gb + k0 + 32,                 nb + 4096 + t * 8);
            GLOAD_LDS16(gb + k0 + 32 + 64 * Bstride,  nb + 4096 + 2048 + t * 8);
        }
        s16x8 af[4], bf[4];
        #pragma unroll
        for (int i = 0; i < 4; i++)
            af[i] = *(const s16x8*)(buf + (wm + i * 16 + c) * 32 + quad * 8);
        #pragma unroll
        for (int i = 0; i < 4; i++)
            bf[i] = *(const s16x8*)(buf + 4096 + (wn + i * 16 + c) * 32 + quad * 8);
        #pragma unroll
        for (int mt = 0; mt < 4; mt++)
            #pragma unroll
            for (int nt = 0; nt < 4; nt++)
                acc[mt][nt] = MFMA16(af[mt], bf[nt], acc[mt][nt]);
        __syncthreads();   // prefetch complete + all ds_reads retired
        cur ^= 1;
    }
}

// ---------------------------------------------------------------------------
// Kernel 1: convert x -> bf16 row-major; W{q,k,v} -> bf16 transposed [n][k]
// via 64x64 LDS-transpose tiles. Grid 4288: [0,4096) x, [4096,4288) weights.
// ---------------------------------------------------------------------------
__global__ __launch_bounds__(256) void k_convert(
    const float* __restrict__ x, const float* __restrict__ wq,
    const float* __restrict__ wk, const float* __restrict__ wv,
    unsigned short* __restrict__ xbf, unsigned short* __restrict__ wt)
{
    __shared__ __align__(16) unsigned short lt[64][72];   // 64x64 tile, padded

    int bid = blockIdx.x, t = threadIdx.x;
    if (bid < 4096) {
        int gid = bid * 256 + t;
        float4 v = ((const float4*)x)[gid];
        us4 o = { f2bf(v.x), f2bf(v.y), f2bf(v.z), f2bf(v.w) };
        ((us4*)xbf)[gid] = o;
    } else {
        int idx = bid - 4096;
        int w = idx >> 6;                    // 0=q 1=k 2=v
        int tile = idx & 63;
        int tk = tile >> 3, tn = tile & 7;   // 8x8 tiles of 64x64 over [512][512]
        const float* src = ((w == 0) ? wq : (w == 1) ? wk : wv)
                         + (size_t)(tk * 64) * 512 + tn * 64;

        int row = t >> 2;
        int c0 = (t & 3) * 16;
        const float4* s = (const float4*)(src + (size_t)row * 512 + c0);
        #pragma unroll
        for (int q = 0; q < 4; q++) {
            float4 v = s[q];
            lt[c0 + q * 4 + 0][row] = f2bf(v.x);
            lt[c0 + q * 4 + 1][row] = f2bf(v.y);
            lt[c0 + q * 4 + 2][row] = f2bf(v.z);
            lt[c0 + q * 4 + 3][row] = f2bf(v.w);
        }
        __syncthreads();

        int n = t >> 2;
        int k0 = (t & 3) * 16;
        s16x8 a = *(const s16x8*)&lt[n][k0];
        s16x8 b = *(const s16x8*)&lt[n][k0 + 8];
        unsigned short* dst = wt + (((size_t)(w * 512 + tn * 64 + n)) << 9)
                                 + tk * 64 + k0;
        *(s16x8*)dst = a;
        *(s16x8*)(dst + 8) = b;
    }
}

// ---------------------------------------------------------------------------
// Kernel 2: QKV projection. [8192x512] @ [1536x512]^T. Grid (64,12).
// All epilogues repack through LDS for coalesced vector stores.
// ---------------------------------------------------------------------------
__global__ __launch_bounds__(256) void k_proj(
    const unsigned short* __restrict__ xbf, const unsigned short* __restrict__ wt,
    unsigned short* __restrict__ qbf, unsigned short* __restrict__ kbf,
    unsigned short* __restrict__ vtbf)
{
    __shared__ __align__(16) unsigned short sh[SH128];

    int t = threadIdx.x;
    int m0 = blockIdx.x * 128, n0 = blockIdx.y * 128;
    f32x4 acc[4][4] = {};

    gemm_core128_db(xbf + (size_t)m0 * 512, 512, wt + (size_t)n0 * 512, 512,
                    512, sh, t, acc);
    // core ends with a barrier; sh is reusable now

    int wave = t >> 6, lane = t & 63, c = lane & 15, quad = lane >> 4;
    int wm = (wave >> 1) * 64, wn = (wave & 1) * 64;
    int sel = blockIdx.y >> 2;                    // 0=q 1=k 2=v

    if (sel < 2) {
        unsigned short* dst = sel ? kbf : qbf;
        int ncol0 = n0 - sel * 512;
        #pragma unroll
        for (int mt = 0; mt < 4; mt++)
            #pragma unroll
            for (int nt = 0; nt < 4; nt++)
                #pragma unroll
                for (int r = 0; r < 4; r++)
                    sh[(wm + mt * 16 + quad * 4 + r) * RP + wn + nt * 16 + c]
                        = f2bf(acc[mt][nt][r]);
        __syncthreads();
        // each thread owns 64 shorts = 8 vectors (full tile coverage)
        int rr = t >> 1, hh = (t & 1) * 64;
        const s16x8* sp = (const s16x8*)(sh + rr * RP + hh);
        s16x8* dp = (s16x8*)(dst + (size_t)(m0 + rr) * 512 + ncol0 + hh);
        s16x8 v[8];
        #pragma unroll
        for (int i = 0; i < 8; i++) v[i] = sp[i];
        #pragma unroll
        for (int i = 0; i < 8; i++) dp[i] = v[i];
    } else {
        // V: repack transposed in LDS -> 128B-contiguous stores per thread.
        #pragma unroll
        for (int mt = 0; mt < 4; mt++)
            #pragma unroll
            for (int nt = 0; nt < 4; nt++)
                #pragma unroll
                for (int r = 0; r < 4; r++)
                    sh[(wn + nt * 16 + c) * RP + wm + mt * 16 + quad * 4 + r]
                        = f2bf(acc[mt][nt][r]);
        __syncthreads();
        int bb = m0 >> 11, nn0 = m0 & 2047;
        int dbase = n0 - 1024;
        int dl = t >> 1, nh = (t & 1) * 64;
        const s16x8* sp = (const s16x8*)(sh + dl * RP + nh);
        s16x8* dp = (s16x8*)(vtbf + ((size_t)(bb * 512 + dbase + dl)) * 2048
                                  + nn0 + nh);
        s16x8 v[8];
        #pragma unroll
        for (int i = 0; i < 8; i++) v[i] = sp[i];
        #pragma unroll
        for (int i = 0; i < 8; i++) dp[i] = v[i];
    }
}

// ---------------------------------------------------------------------------
// score body: S = Q@K^T (128x128 tile), P = exp(S*scale) -> bf16 via LDS
// repack (coalesced 16B stores). No l accumulation — k_out self-computes it.
// ---------------------------------------------------------------------------
__device__ __forceinline__ void score_body(
    const unsigned short* __restrict__ qbf, const unsigned short* __restrict__ kbf,
    unsigned short* __restrict__ pbf,
    int b, int m0, int n0, int t, unsigned short* sh)
{
    f32x4 acc[4][4] = {};
    gemm_core128_db(qbf + (size_t)(b * 2048 + m0) * 512, 512,
                    kbf + (size_t)(b * 2048 + n0) * 512, 512,
                    512, sh, t, acc);
    // core ends with a barrier; sh is reusable now

    int wave = t >> 6, lane = t & 63, c = lane & 15, quad = lane >> 4;
    int wm = (wave >> 1) * 64, wn = (wave & 1) * 64;
    const float scale = 0.044194173824159216f;    // 1/sqrt(512)

    #pragma unroll
    for (int mt = 0; mt < 4; mt++) {
        #pragma unroll
        for (int r = 0; r < 4; r++) {
            int row = wm + mt * 16 + quad * 4 + r;    // local 0..127
            #pragma unroll
            for (int nt = 0; nt < 4; nt++) {
                float p = __expf(acc[mt][nt][r] * scale);
                sh[row * RP + wn + nt * 16 + c] = f2bf(p);
            }
        }
    }
    __syncthreads();
    // 8 vectors per thread (64 shorts), full tile coverage.
    int rr = t >> 1, hh = (t & 1) * 64;
    const s16x8* sp = (const s16x8*)(sh + rr * RP + hh);
    s16x8* dp = (s16x8*)(pbf + (size_t)(b * 2048 + m0 + rr) * 2048 + n0 + hh);
    s16x8 v[8];
    #pragma unroll
    for (int i = 0; i < 8; i++) v[i] = sp[i];
    #pragma unroll
    for (int i = 0; i < 8; i++) dp[i] = v[i];
}

// ---------------------------------------------------------------------------
// prior: one WAVE per (b,i) row — no LDS, no barriers, no atomics.
// ---------------------------------------------------------------------------
__device__ __forceinline__ void prior_wave(
    const float* __restrict__ x, const float* __restrict__ wsv,
    float* __restrict__ pout, int row, int lane)
{
    const float4* xr = (const float4*)(x + (size_t)row * 512);
    const float4* wr = (const float4*)wsv;
    float4 a0 = xr[lane * 2],     b0 = wr[lane * 2];
    float4 a1 = xr[lane * 2 + 1], b1 = wr[lane * 2 + 1];
    float part = a0.x * b0.x + a0.y * b0.y + a0.z * b0.z + a0.w * b0.w
               + a1.x * b1.x + a1.y * b1.y + a1.z * b1.z + a1.w * b1.w;
    #pragma unroll
    for (int o = 32; o; o >>= 1) part += __shfl_xor(part, o, 64);
    float sigma = part;
    float inv2 = 0.5f / (sigma * sigma);

    int i = row & 2047;
    float g[32];
    float sum = 0.f;
    #pragma unroll
    for (int u = 0; u < 8; u++) {
        #pragma unroll
        for (int v = 0; v < 4; v++) {
            float d = (float)(u * 256 + lane * 4 + v - i);
            float e = __expf(-(d * d) * inv2);
            g[u * 4 + v] = e;
            sum += e;
        }
    }
    #pragma unroll
    for (int o = 32; o; o >>= 1) sum += __shfl_xor(sum, o, 64);
    float inv = 1.0f / sum;

    float4* pr = (float4*)(pout + (size_t)row * 2048);
    #pragma unroll
    for (int u = 0; u < 8; u++) {
        float4 o4 = { g[u * 4] * inv, g[u * 4 + 1] * inv,
                      g[u * 4 + 2] * inv, g[u * 4 + 3] * inv };
        pr[u * 64 + lane] = o4;
    }
}

// ---------------------------------------------------------------------------
// Kernel 3a (ws path): merged score + prior. Grid 3072 1D.
// ---------------------------------------------------------------------------
__global__ __launch_bounds__(256) void k_score_prior(
    const unsigned short* __restrict__ qbf, const unsigned short* __restrict__ kbf,
    unsigned short* __restrict__ pbf,
    const float* __restrict__ x, const float* __restrict__ wsv,
    float* __restrict__ pout)
{
    __shared__ __align__(16) unsigned short sh[SH128];

    int bid = blockIdx.x, t = threadIdx.x;
    if (bid < 1024) {
        int b = bid >> 8, r = bid & 255;
        score_body(qbf, kbf, pbf, b, (r & 15) * 128, (r >> 4) * 128, t, sh);
    } else {
        int row = (bid - 1024) * 4 + (t >> 6);
        prior_wave(x, wsv, pout, row, t & 63);
    }
}

// ---------------------------------------------------------------------------
// Kernel 3b (fallback): standalone score. Grid (16,16,4).
// ---------------------------------------------------------------------------
__global__ __launch_bounds__(256) void k_score(
    const unsigned short* __restrict__ qbf, const unsigned short* __restrict__ kbf,
    unsigned short* __restrict__ pbf)
{
    __shared__ __align__(16) unsigned short sh[SH128];
    score_body(qbf, kbf, pbf, blockIdx.z,
               blockIdx.x * 128, blockIdx.y * 128, threadIdx.x, sh);
}

// ---------------------------------------------------------------------------
// Kernel 4: output. Per batch: O = P @ Vt^T / l. 128x64 tile, grid (16,8,4).
// Double-buffered staging (one barrier per K-step, 64 steps). l computed
// in-kernel via a 5th accumulator column with an all-ones bf16 B fragment.
// sh layout: buf0 A[0,4096) B[4096,6144), buf1 at +6144.
// ---------------------------------------------------------------------------
__global__ __launch_bounds__(256) void k_out(
    const unsigned short* __restrict__ pbf, const unsigned short* __restrict__ vtbf,
    float* __restrict__ zout)
{
    __shared__ __align__(16) unsigned short sh[12288];

    int t = threadIdx.x;
    int b = blockIdx.z;
    int m0 = blockIdx.x * 128, n0 = blockIdx.y * 64;

    const int wave = t >> 6, lane = t & 63;
    const int c = lane & 15, quad = lane >> 4;
    const int wm = (wave >> 1) * 64, wn = (wave & 1) * 32;
    const int srow = t >> 2;
    const int scol = (t & 3) * 8;

    const unsigned short* ga = pbf + (size_t)(b * 2048 + m0 + srow) * 2048 + scol;
    const unsigned short* gb = vtbf + (size_t)(b * 512 + n0 + srow) * 2048 + scol;

    s16x8 ones;
    #pragma unroll
    for (int i = 0; i < 8; i++) ones[i] = (short)0x3F80;    // bf16 1.0

    f32x4 acc[4][2] = {};
    f32x4 accl[4] = {};

    // prologue: stage k0=0 into buf0
    GLOAD_LDS16(ga,             sh + t * 8);
    GLOAD_LDS16(ga + 64 * 2048, sh + 2048 + t * 8);
    GLOAD_LDS16(gb,             sh + 4096 + t * 8);
    __syncthreads();

    int cur = 0;
    for (int k0 = 0; k0 < 2048; k0 += 32) {
        const unsigned short* buf = sh + cur * 6144;
        if (k0 + 32 < 2048) {
            unsigned short* nb = sh + (cur ^ 1) * 6144;
            GLOAD_LDS16(ga + k0 + 32,             nb + t * 8);
            GLOAD_LDS16(ga + k0 + 32 + 64 * 2048, nb + 2048 + t * 8);
            GLOAD_LDS16(gb + k0 + 32,             nb + 4096 + t * 8);
        }
        s16x8 af[4], bf[2];
        #pragma unroll
        for (int i = 0; i < 4; i++)
            af[i] = *(const s16x8*)(buf + (wm + i * 16 + c) * 32 + quad * 8);
        #pragma unroll
        for (int i = 0; i < 2; i++)
            bf[i] = *(const s16x8*)(buf + 4096 + (wn + i * 16 + c) * 32 + quad * 8);
        #pragma unroll
        for (int mt = 0; mt < 4; mt++) {
            #pragma unroll
            for (int nt = 0; nt < 2; nt++)
                acc[mt][nt] = MFMA16(af[mt], bf[nt], acc[mt][nt]);
            accl[mt] = MFMA16(af[mt], ones, accl[mt]);
        }
        __syncthreads();
        cur ^= 1;
    }

    #pragma unroll
    for (int mt = 0; mt < 4; mt++) {
        #pragma unroll
        for (int r = 0; r < 4; r++) {
            int row = wm + mt * 16 + quad * 4 + r;
            float inv = 1.0f / accl[mt][r];
            #pragma unroll
            for (int nt = 0; nt < 2; nt++) {
                zout[(size_t)(b * 2048 + m0 + row) * 512 + n0 + wn + nt * 16 + c]
                    = acc[mt][nt][r] * inv;
            }
        }
    }
}

// ---------------------------------------------------------------------------
// Kernel 5 (fallback): standalone prior. Grid 2048, 4 rows/block.
// ---------------------------------------------------------------------------
__global__ __launch_bounds__(256) void k_prior(
    const float* __restrict__ x, const float* __restrict__ wsv,
    float* __restrict__ pout)
{
    int row = blockIdx.x * 4 + (threadIdx.x >> 6);
    prior_wave(x, wsv, pout, row, threadIdx.x & 63);
}

// ---------------------------------------------------------------------------
extern "C" void kernel_launch(void* const* d_in, const int* in_sizes, int n_in,
                              void* d_out, int out_size, void* d_ws, size_t ws_size,
                              hipStream_t stream)
{
    const float* x  = (const float*)d_in[0];
    const float* wq = (const float*)d_in[1];
    const float* wk = (const float*)d_in[2];
    const float* wv = (const float*)d_in[3];
    const float* ws = (const float*)d_in[4];

    float* zout = (float*)d_out;                       // (4,2048,512)
    float* pout = zout + (size_t)4 * 2048 * 512;       // (4,2048,2048) = 67.1 MB

    // Scratch: xbf 4.19M + wt 0.79M + q/k/vt 3*4.19M + pbf 16.78M ushorts.
    const size_t need = ((size_t)4194304 + 786432 + 3 * 4194304 + 16777216) * 2;

    if (ws_size >= need) {
        // ---- ws path: all scratch in d_ws; pout free -> prior overlaps score
        unsigned short* base = (unsigned short*)d_ws;
        unsigned short* xbf  = base;
        unsigned short* wt   = xbf  + (size_t)4194304;
        unsigned short* qbf  = wt   + (size_t)786432;
        unsigned short* kbf  = qbf  + (size_t)4194304;
        unsigned short* vtbf = kbf  + (size_t)4194304;
        unsigned short* pbf  = vtbf + (size_t)4194304;

        k_convert<<<dim3(4288), dim3(256), 0, stream>>>(x, wq, wk, wv, xbf, wt);
        k_proj       <<<dim3(64, 12),   dim3(256), 0, stream>>>(xbf, wt, qbf, kbf, vtbf);
        k_score_prior<<<dim3(3072),     dim3(256), 0, stream>>>(qbf, kbf, pbf, x, ws, pout);
        k_out        <<<dim3(16, 8, 4), dim3(256), 0, stream>>>(pbf, vtbf, zout);
    } else {
        // ---- fallback: scratch inside pout (prior runs last)
        unsigned short* base = (unsigned short*)pout;
        unsigned short* pbf  = base;                        // 16,777,216
        unsigned short* qbf  = base + (size_t)16777216;
        unsigned short* kbf  = qbf  + (size_t)4194304;
        unsigned short* vtbf = kbf  + (size_t)4194304;
        unsigned short* xbf  = base;                        // overlaps pbf (ok)
        unsigned short* wt   = base + (size_t)4194304;      // overlaps pbf (ok)

        k_convert<<<dim3(4288), dim3(256), 0, stream>>>(x, wq, wk, wv, xbf, wt);
        k_proj  <<<dim3(64, 12),    dim3(256), 0, stream>>>(xbf, wt, qbf, kbf, vtbf);
        k_score <<<dim3(16, 16, 4), dim3(256), 0, stream>>>(qbf, kbf, pbf);
        k_out   <<<dim3(16, 8, 4),  dim3(256), 0, stream>>>(pbf, vtbf, zout);
        k_prior <<<dim3(2048),      dim3(256), 0, stream>>>(x, ws, pout);
    }
}

// Round 6
// 198.187 us; speedup vs baseline: 1.0413x; 1.0048x over previous
//
#include <hip/hip_runtime.h>

typedef float f32x4 __attribute__((ext_vector_type(4)));
typedef short s16x8 __attribute__((ext_vector_type(8)));
typedef unsigned short us4 __attribute__((ext_vector_type(4)));

#define MFMA16(a, b, c) __builtin_amdgcn_mfma_f32_16x16x32_bf16(a, b, c, 0, 0, 0)

// async global->LDS DMA, 16B per lane. LDS dest must be wave-uniform base + lane*16.
#define GLOAD_LDS16(gp, lp) __builtin_amdgcn_global_load_lds( \
    (__attribute__((address_space(1))) void*)(gp),            \
    (__attribute__((address_space(3))) void*)(lp), 16, 0, 0)

__device__ __forceinline__ unsigned short f2bf(float f) {
    union { float f; unsigned u; } v; v.f = f;
    unsigned r = v.u + 0x7fffu + ((v.u >> 16) & 1u);   // RNE truncate to bf16
    return (unsigned short)(r >> 16);
}

// Repack tile row stride: 136 shorts = 272B (16B-aligned rows, odd-ish bank
// stride so scalar ds_writes are ~2-way and b128 readback ~4-way).
#define RP 136
// shared size for 128x128 GEMM kernels:
// dbuf gemm needs 16384 shorts, repack needs 128*RP = 17408.
#define SH128 (128 * RP)

// ---------------------------------------------------------------------------
// Counted-vmcnt double-buffered GEMM core (T3+T4), 128x128 tile:
// C += A[128xK] @ B[128xK]^T. Two tiles permanently in flight:
//   prologue: tile0 -> buf0, tile1 -> buf1            (vmcnt = 8/wave)
//   iter i:   s_waitcnt vmcnt(4)  -> oldest 4 (tile i) landed (m135 order)
//             s_barrier           -> ALL waves' tile-i loads landed
//             ds_read frags; lgkmcnt(0)+sched_barrier (rule #18); 16 MFMA
//             s_barrier           -> all reads of buf[i&1] retired
//             issue tile i+2 -> buf[i&1]              (vmcnt back to 8)
// Loads get a full iteration (+2 barriers) to complete instead of the
// __syncthreads vmcnt(0) drain that serialized R5.
// Ends with vmcnt==0 and a trailing barrier -> callers may reuse sh.
// ---------------------------------------------------------------------------
__device__ __forceinline__ void gemm_core128_cnt(
    const unsigned short* __restrict__ Ab, size_t Astride,
    const unsigned short* __restrict__ Bb, size_t Bstride,
    int K, unsigned short* sh, int t, f32x4 acc[4][4])
{
    const int wave = t >> 6, lane = t & 63;
    const int c = lane & 15, quad = lane >> 4;
    const int wm = (wave >> 1) * 64, wn = (wave & 1) * 64;
    const int srow = t >> 2;
    const int scol = (t & 3) * 8;

    const unsigned short* ga = Ab + (size_t)srow * Astride + scol;
    const unsigned short* gb = Bb + (size_t)srow * Bstride + scol;

    // prologue: tile0 -> buf0
    GLOAD_LDS16(ga,                 sh + t * 8);
    GLOAD_LDS16(ga + 64 * Astride,  sh + 2048 + t * 8);
    GLOAD_LDS16(gb,                 sh + 4096 + t * 8);
    GLOAD_LDS16(gb + 64 * Bstride,  sh + 6144 + t * 8);
    if (32 < K) {   // tile1 -> buf1
        GLOAD_LDS16(ga + 32,                 sh + 8192 + t * 8);
        GLOAD_LDS16(ga + 32 + 64 * Astride,  sh + 8192 + 2048 + t * 8);
        GLOAD_LDS16(gb + 32,                 sh + 8192 + 4096 + t * 8);
        GLOAD_LDS16(gb + 32 + 64 * Bstride,  sh + 8192 + 6144 + t * 8);
    }

    int cur = 0;
    for (int k0 = 0; k0 < K; k0 += 32) {
        if (k0 + 32 < K) asm volatile("s_waitcnt vmcnt(4)" ::: "memory");
        else             asm volatile("s_waitcnt vmcnt(0)" ::: "memory");
        __builtin_amdgcn_s_barrier();              // tile k0 visible to all
        __builtin_amdgcn_sched_barrier(0);         // no ds_read hoists above

        const unsigned short* buf = sh + cur * 8192;
        s16x8 af[4], bf[4];
        #pragma unroll
        for (int i = 0; i < 4; i++)
            af[i] = *(const s16x8*)(buf + (wm + i * 16 + c) * 32 + quad * 8);
        #pragma unroll
        for (int i = 0; i < 4; i++)
            bf[i] = *(const s16x8*)(buf + 4096 + (wn + i * 16 + c) * 32 + quad * 8);

        asm volatile("s_waitcnt lgkmcnt(0)" ::: "memory");
        __builtin_amdgcn_sched_barrier(0);         // rule #18: pin MFMA below

        #pragma unroll
        for (int mt = 0; mt < 4; mt++)
            #pragma unroll
            for (int nt = 0; nt < 4; nt++)
                acc[mt][nt] = MFMA16(af[mt], bf[nt], acc[mt][nt]);

        __builtin_amdgcn_s_barrier();              // all reads of buf retired
        __builtin_amdgcn_sched_barrier(0);         // no prefetch hoists above

        if (k0 + 64 < K) {                         // tile i+2 -> just-freed buf
            unsigned short* nb = sh + cur * 8192;
            GLOAD_LDS16(ga + k0 + 64,                 nb + t * 8);
            GLOAD_LDS16(ga + k0 + 64 + 64 * Astride,  nb + 2048 + t * 8);
            GLOAD_LDS16(gb + k0 + 64,                 nb + 4096 + t * 8);
            GLOAD_LDS16(gb + k0 + 64 + 64 * Bstride,  nb + 6144 + t * 8);
        }
        cur ^= 1;
    }
}

// ---------------------------------------------------------------------------
// Kernel 1: convert x -> bf16 row-major; W{q,k,v} -> bf16 transposed [n][k]
// via 64x64 LDS-transpose tiles. Grid 4288: [0,4096) x, [4096,4288) weights.
// ---------------------------------------------------------------------------
__global__ __launch_bounds__(256) void k_convert(
    const float* __restrict__ x, const float* __restrict__ wq,
    const float* __restrict__ wk, const float* __restrict__ wv,
    unsigned short* __restrict__ xbf, unsigned short* __restrict__ wt)
{
    __shared__ __align__(16) unsigned short lt[64][72];   // 64x64 tile, padded

    int bid = blockIdx.x, t = threadIdx.x;
    if (bid < 4096) {
        int gid = bid * 256 + t;
        float4 v = ((const float4*)x)[gid];
        us4 o = { f2bf(v.x), f2bf(v.y), f2bf(v.z), f2bf(v.w) };
        ((us4*)xbf)[gid] = o;
    } else {
        int idx = bid - 4096;
        int w = idx >> 6;                    // 0=q 1=k 2=v
        int tile = idx & 63;
        int tk = tile >> 3, tn = tile & 7;   // 8x8 tiles of 64x64 over [512][512]
        const float* src = ((w == 0) ? wq : (w == 1) ? wk : wv)
                         + (size_t)(tk * 64) * 512 + tn * 64;

        int row = t >> 2;
        int c0 = (t & 3) * 16;
        const float4* s = (const float4*)(src + (size_t)row * 512 + c0);
        #pragma unroll
        for (int q = 0; q < 4; q++) {
            float4 v = s[q];
            lt[c0 + q * 4 + 0][row] = f2bf(v.x);
            lt[c0 + q * 4 + 1][row] = f2bf(v.y);
            lt[c0 + q * 4 + 2][row] = f2bf(v.z);
            lt[c0 + q * 4 + 3][row] = f2bf(v.w);
        }
        __syncthreads();

        int n = t >> 2;
        int k0 = (t & 3) * 16;
        s16x8 a = *(const s16x8*)&lt[n][k0];
        s16x8 b = *(const s16x8*)&lt[n][k0 + 8];
        unsigned short* dst = wt + (((size_t)(w * 512 + tn * 64 + n)) << 9)
                                 + tk * 64 + k0;
        *(s16x8*)dst = a;
        *(s16x8*)(dst + 8) = b;
    }
}

// ---------------------------------------------------------------------------
// Kernel 2: QKV projection. [8192x512] @ [1536x512]^T. Grid (64,12).
// All epilogues repack through LDS for coalesced vector stores.
// ---------------------------------------------------------------------------
__global__ __launch_bounds__(256) void k_proj(
    const unsigned short* __restrict__ xbf, const unsigned short* __restrict__ wt,
    unsigned short* __restrict__ qbf, unsigned short* __restrict__ kbf,
    unsigned short* __restrict__ vtbf)
{
    __shared__ __align__(16) unsigned short sh[SH128];

    int t = threadIdx.x;
    int m0 = blockIdx.x * 128, n0 = blockIdx.y * 128;
    f32x4 acc[4][4] = {};

    gemm_core128_cnt(xbf + (size_t)m0 * 512, 512, wt + (size_t)n0 * 512, 512,
                     512, sh, t, acc);
    // core ends with a barrier + vmcnt drained; sh is reusable now

    int wave = t >> 6, lane = t & 63, c = lane & 15, quad = lane >> 4;
    int wm = (wave >> 1) * 64, wn = (wave & 1) * 64;
    int sel = blockIdx.y >> 2;                    // 0=q 1=k 2=v

    if (sel < 2) {
        unsigned short* dst = sel ? kbf : qbf;
        int ncol0 = n0 - sel * 512;
        #pragma unroll
        for (int mt = 0; mt < 4; mt++)
            #pragma unroll
            for (int nt = 0; nt < 4; nt++)
                #pragma unroll
                for (int r = 0; r < 4; r++)
                    sh[(wm + mt * 16 + quad * 4 + r) * RP + wn + nt * 16 + c]
                        = f2bf(acc[mt][nt][r]);
        __syncthreads();
        // each thread owns 64 shorts = 8 vectors (full tile coverage)
        int rr = t >> 1, hh = (t & 1) * 64;
        const s16x8* sp = (const s16x8*)(sh + rr * RP + hh);
        s16x8* dp = (s16x8*)(dst + (size_t)(m0 + rr) * 512 + ncol0 + hh);
        s16x8 v[8];
        #pragma unroll
        for (int i = 0; i < 8; i++) v[i] = sp[i];
        #pragma unroll
        for (int i = 0; i < 8; i++) dp[i] = v[i];
    } else {
        // V: repack transposed in LDS -> 128B-contiguous stores per thread.
        #pragma unroll
        for (int mt = 0; mt < 4; mt++)
            #pragma unroll
            for (int nt = 0; nt < 4; nt++)
                #pragma unroll
                for (int r = 0; r < 4; r++)
                    sh[(wn + nt * 16 + c) * RP + wm + mt * 16 + quad * 4 + r]
                        = f2bf(acc[mt][nt][r]);
        __syncthreads();
        int bb = m0 >> 11, nn0 = m0 & 2047;
        int dbase = n0 - 1024;
        int dl = t >> 1, nh = (t & 1) * 64;
        const s16x8* sp = (const s16x8*)(sh + dl * RP + nh);
        s16x8* dp = (s16x8*)(vtbf + ((size_t)(bb * 512 + dbase + dl)) * 2048
                                  + nn0 + nh);
        s16x8 v[8];
        #pragma unroll
        for (int i = 0; i < 8; i++) v[i] = sp[i];
        #pragma unroll
        for (int i = 0; i < 8; i++) dp[i] = v[i];
    }
}

// ---------------------------------------------------------------------------
// score body: S = Q@K^T (128x128 tile), P = exp(S*scale) -> bf16 via LDS
// repack (coalesced 16B stores). No l accumulation — k_out self-computes it.
// ---------------------------------------------------------------------------
__device__ __forceinline__ void score_body(
    const unsigned short* __restrict__ qbf, const unsigned short* __restrict__ kbf,
    unsigned short* __restrict__ pbf,
    int b, int m0, int n0, int t, unsigned short* sh)
{
    f32x4 acc[4][4] = {};
    gemm_core128_cnt(qbf + (size_t)(b * 2048 + m0) * 512, 512,
                     kbf + (size_t)(b * 2048 + n0) * 512, 512,
                     512, sh, t, acc);
    // core ends with a barrier + vmcnt drained; sh is reusable now

    int wave = t >> 6, lane = t & 63, c = lane & 15, quad = lane >> 4;
    int wm = (wave >> 1) * 64, wn = (wave & 1) * 64;
    const float scale = 0.044194173824159216f;    // 1/sqrt(512)

    #pragma unroll
    for (int mt = 0; mt < 4; mt++) {
        #pragma unroll
        for (int r = 0; r < 4; r++) {
            int row = wm + mt * 16 + quad * 4 + r;    // local 0..127
            #pragma unroll
            for (int nt = 0; nt < 4; nt++) {
                float p = __expf(acc[mt][nt][r] * scale);
                sh[row * RP + wn + nt * 16 + c] = f2bf(p);
            }
        }
    }
    __syncthreads();
    // 8 vectors per thread (64 shorts), full tile coverage.
    int rr = t >> 1, hh = (t & 1) * 64;
    const s16x8* sp = (const s16x8*)(sh + rr * RP + hh);
    s16x8* dp = (s16x8*)(pbf + (size_t)(b * 2048 + m0 + rr) * 2048 + n0 + hh);
    s16x8 v[8];
    #pragma unroll
    for (int i = 0; i < 8; i++) v[i] = sp[i];
    #pragma unroll
    for (int i = 0; i < 8; i++) dp[i] = v[i];
}

// ---------------------------------------------------------------------------
// prior: one WAVE per (b,i) row — no LDS, no barriers, no atomics.
// ---------------------------------------------------------------------------
__device__ __forceinline__ void prior_wave(
    const float* __restrict__ x, const float* __restrict__ wsv,
    float* __restrict__ pout, int row, int lane)
{
    const float4* xr = (const float4*)(x + (size_t)row * 512);
    const float4* wr = (const float4*)wsv;
    float4 a0 = xr[lane * 2],     b0 = wr[lane * 2];
    float4 a1 = xr[lane * 2 + 1], b1 = wr[lane * 2 + 1];
    float part = a0.x * b0.x + a0.y * b0.y + a0.z * b0.z + a0.w * b0.w
               + a1.x * b1.x + a1.y * b1.y + a1.z * b1.z + a1.w * b1.w;
    #pragma unroll
    for (int o = 32; o; o >>= 1) part += __shfl_xor(part, o, 64);
    float sigma = part;
    float inv2 = 0.5f / (sigma * sigma);

    int i = row & 2047;
    float g[32];
    float sum = 0.f;
    #pragma unroll
    for (int u = 0; u < 8; u++) {
        #pragma unroll
        for (int v = 0; v < 4; v++) {
            float d = (float)(u * 256 + lane * 4 + v - i);
            float e = __expf(-(d * d) * inv2);
            g[u * 4 + v] = e;
            sum += e;
        }
    }
    #pragma unroll
    for (int o = 32; o; o >>= 1) sum += __shfl_xor(sum, o, 64);
    float inv = 1.0f / sum;

    float4* pr = (float4*)(pout + (size_t)row * 2048);
    #pragma unroll
    for (int u = 0; u < 8; u++) {
        float4 o4 = { g[u * 4] * inv, g[u * 4 + 1] * inv,
                      g[u * 4 + 2] * inv, g[u * 4 + 3] * inv };
        pr[u * 64 + lane] = o4;
    }
}

// ---------------------------------------------------------------------------
// Kernel 3a (ws path): merged score + prior. Grid 3072 1D.
// ---------------------------------------------------------------------------
__global__ __launch_bounds__(256) void k_score_prior(
    const unsigned short* __restrict__ qbf, const unsigned short* __restrict__ kbf,
    unsigned short* __restrict__ pbf,
    const float* __restrict__ x, const float* __restrict__ wsv,
    float* __restrict__ pout)
{
    __shared__ __align__(16) unsigned short sh[SH128];

    int bid = blockIdx.x, t = threadIdx.x;
    if (bid < 1024) {
        int b = bid >> 8, r = bid & 255;
        score_body(qbf, kbf, pbf, b, (r & 15) * 128, (r >> 4) * 128, t, sh);
    } else {
        int row = (bid - 1024) * 4 + (t >> 6);
        prior_wave(x, wsv, pout, row, t & 63);
    }
}

// ---------------------------------------------------------------------------
// Kernel 3b (fallback): standalone score. Grid (16,16,4).
// ---------------------------------------------------------------------------
__global__ __launch_bounds__(256) void k_score(
    const unsigned short* __restrict__ qbf, const unsigned short* __restrict__ kbf,
    unsigned short* __restrict__ pbf)
{
    __shared__ __align__(16) unsigned short sh[SH128];
    score_body(qbf, kbf, pbf, blockIdx.z,
               blockIdx.x * 128, blockIdx.y * 128, threadIdx.x, sh);
}

// ---------------------------------------------------------------------------
// Kernel 4: output. Per batch: O = P @ Vt^T / l. 128x64 tile, grid (16,8,4).
// Counted-vmcnt double-buffered staging (3 loads/tile, vmcnt(3) steady).
// l computed in-kernel via a 5th accumulator column with all-ones bf16 B.
// sh layout: buf0 A[0,4096) B[4096,6144), buf1 at +6144.
// ---------------------------------------------------------------------------
__global__ __launch_bounds__(256) void k_out(
    const unsigned short* __restrict__ pbf, const unsigned short* __restrict__ vtbf,
    float* __restrict__ zout)
{
    __shared__ __align__(16) unsigned short sh[12288];

    int t = threadIdx.x;
    int b = blockIdx.z;
    int m0 = blockIdx.x * 128, n0 = blockIdx.y * 64;

    const int wave = t >> 6, lane = t & 63;
    const int c = lane & 15, quad = lane >> 4;
    const int wm = (wave >> 1) * 64, wn = (wave & 1) * 32;
    const int srow = t >> 2;
    const int scol = (t & 3) * 8;

    const unsigned short* ga = pbf + (size_t)(b * 2048 + m0 + srow) * 2048 + scol;
    const unsigned short* gb = vtbf + (size_t)(b * 512 + n0 + srow) * 2048 + scol;

    s16x8 ones;
    #pragma unroll
    for (int i = 0; i < 8; i++) ones[i] = (short)0x3F80;    // bf16 1.0

    f32x4 acc[4][2] = {};
    f32x4 accl[4] = {};

    // prologue: tile0 -> buf0, tile1 -> buf1 (vmcnt = 6)
    GLOAD_LDS16(ga,                  sh + t * 8);
    GLOAD_LDS16(ga + 64 * 2048,      sh + 2048 + t * 8);
    GLOAD_LDS16(gb,                  sh + 4096 + t * 8);
    GLOAD_LDS16(ga + 32,             sh + 6144 + t * 8);
    GLOAD_LDS16(ga + 32 + 64 * 2048, sh + 6144 + 2048 + t * 8);
    GLOAD_LDS16(gb + 32,             sh + 6144 + 4096 + t * 8);

    int cur = 0;
    for (int k0 = 0; k0 < 2048; k0 += 32) {
        if (k0 + 32 < 2048) asm volatile("s_waitcnt vmcnt(3)" ::: "memory");
        else                asm volatile("s_waitcnt vmcnt(0)" ::: "memory");
        __builtin_amdgcn_s_barrier();
        __builtin_amdgcn_sched_barrier(0);

        const unsigned short* buf = sh + cur * 6144;
        s16x8 af[4], bf[2];
        #pragma unroll
        for (int i = 0; i < 4; i++)
            af[i] = *(const s16x8*)(buf + (wm + i * 16 + c) * 32 + quad * 8);
        #pragma unroll
        for (int i = 0; i < 2; i++)
            bf[i] = *(const s16x8*)(buf + 4096 + (wn + i * 16 + c) * 32 + quad * 8);

        asm volatile("s_waitcnt lgkmcnt(0)" ::: "memory");
        __builtin_amdgcn_sched_barrier(0);

        #pragma unroll
        for (int mt = 0; mt < 4; mt++) {
            #pragma unroll
            for (int nt = 0; nt < 2; nt++)
                acc[mt][nt] = MFMA16(af[mt], bf[nt], acc[mt][nt]);
            accl[mt] = MFMA16(af[mt], ones, accl[mt]);
        }

        __builtin_amdgcn_s_barrier();
        __builtin_amdgcn_sched_barrier(0);

        if (k0 + 64 < 2048) {
            unsigned short* nb = sh + cur * 6144;
            GLOAD_LDS16(ga + k0 + 64,             nb + t * 8);
            GLOAD_LDS16(ga + k0 + 64 + 64 * 2048, nb + 2048 + t * 8);
            GLOAD_LDS16(gb + k0 + 64,             nb + 4096 + t * 8);
        }
        cur ^= 1;
    }

    #pragma unroll
    for (int mt = 0; mt < 4; mt++) {
        #pragma unroll
        for (int r = 0; r < 4; r++) {
            int row = wm + mt * 16 + quad * 4 + r;
            float inv = 1.0f / accl[mt][r];
            #pragma unroll
            for (int nt = 0; nt < 2; nt++) {
                zout[(size_t)(b * 2048 + m0 + row) * 512 + n0 + wn + nt * 16 + c]
                    = acc[mt][nt][r] * inv;
            }
        }
    }
}

// ---------------------------------------------------------------------------
// Kernel 5 (fallback): standalone prior. Grid 2048, 4 rows/block.
// ---------------------------------------------------------------------------
__global__ __launch_bounds__(256) void k_prior(
    const float* __restrict__ x, const float* __restrict__ wsv,
    float* __restrict__ pout)
{
    int row = blockIdx.x * 4 + (threadIdx.x >> 6);
    prior_wave(x, wsv, pout, row, threadIdx.x & 63);
}

// ---------------------------------------------------------------------------
extern "C" void kernel_launch(void* const* d_in, const int* in_sizes, int n_in,
                              void* d_out, int out_size, void* d_ws, size_t ws_size,
                              hipStream_t stream)
{
    const float* x  = (const float*)d_in[0];
    const float* wq = (const float*)d_in[1];
    const float* wk = (const float*)d_in[2];
    const float* wv = (const float*)d_in[3];
    const float* ws = (const float*)d_in[4];

    float* zout = (float*)d_out;                       // (4,2048,512)
    float* pout = zout + (size_t)4 * 2048 * 512;       // (4,2048,2048) = 67.1 MB

    // Scratch: xbf 4.19M + wt 0.79M + q/k/vt 3*4.19M + pbf 16.78M ushorts.
    const size_t need = ((size_t)4194304 + 786432 + 3 * 4194304 + 16777216) * 2;

    if (ws_size >= need) {
        // ---- ws path: all scratch in d_ws; pout free -> prior overlaps score
        unsigned short* base = (unsigned short*)d_ws;
        unsigned short* xbf  = base;
        unsigned short* wt   = xbf  + (size_t)4194304;
        unsigned short* qbf  = wt   + (size_t)786432;
        unsigned short* kbf  = qbf  + (size_t)4194304;
        unsigned short* vtbf = kbf  + (size_t)4194304;
        unsigned short* pbf  = vtbf + (size_t)4194304;

        k_convert<<<dim3(4288), dim3(256), 0, stream>>>(x, wq, wk, wv, xbf, wt);
        k_proj       <<<dim3(64, 12),   dim3(256), 0, stream>>>(xbf, wt, qbf, kbf, vtbf);
        k_score_prior<<<dim3(3072),     dim3(256), 0, stream>>>(qbf, kbf, pbf, x, ws, pout);
        k_out        <<<dim3(16, 8, 4), dim3(256), 0, stream>>>(pbf, vtbf, zout);
    } else {
        // ---- fallback: scratch inside pout (prior runs last)
        unsigned short* base = (unsigned short*)pout;
        unsigned short* pbf  = base;                        // 16,777,216
        unsigned short* qbf  = base + (size_t)16777216;
        unsigned short* kbf  = qbf  + (size_t)4194304;
        unsigned short* vtbf = kbf  + (size_t)4194304;
        unsigned short* xbf  = base;                        // overlaps pbf (ok)
        unsigned short* wt   = base + (size_t)4194304;      // overlaps pbf (ok)

        k_convert<<<dim3(4288), dim3(256), 0, stream>>>(x, wq, wk, wv, xbf, wt);
        k_proj  <<<dim3(64, 12),    dim3(256), 0, stream>>>(xbf, wt, qbf, kbf, vtbf);
        k_score <<<dim3(16, 16, 4), dim3(256), 0, stream>>>(qbf, kbf, pbf);
        k_out   <<<dim3(16, 8, 4),  dim3(256), 0, stream>>>(pbf, vtbf, zout);
        k_prior <<<dim3(2048),      dim3(256), 0, stream>>>(x, ws, pout);
    }
}